// Round 5
// baseline (160.420 us; speedup 1.0000x reference)
//
#include <hip/hip_runtime.h>

// MultiHeadAttention_137438953529 on gfx950.
// B=8, S=1024, E=1024, H=16, D=64.  The reference's reshapes are flat
// reinterpretations => attention mixes only groups of 8 consecutive rows of
// the (8192 x 1024) projected matrices, per 64-wide head slice.
//
// R5: deepen the B pipeline to 2 tiles (3-buffer ring).  R4's residual stall:
// glds(kt+1) issued top of iter kt, waited end of iter kt (~1 compute phase of
// slack vs ~300cy latency).  Now iter kt stages glds(kt+2); glds(kt+1) is
// drained for free by the compiler's vmcnt(6) at writeA (FIFO: older than the
// A(kt+1) regs it must wait for).  End-of-iter vmcnt(6) = exactly the 6 ops
// issued this iter -> no-op in steady state.  LDS 40 KiB -> 4 blocks/CU.
// Kept from R3/R4: XCD-family decode (FETCH ~82 MB), source-side chunk XOR
// (0 bank conflicts), cvt_pk A-path, m97 epilogue.

typedef __attribute__((ext_vector_type(4))) float f32x4;
typedef __attribute__((ext_vector_type(8))) short bf16x8;   // MFMA A/B fragment
typedef __attribute__((ext_vector_type(8))) unsigned short u16x8;

#define WAIT_LGKM0 asm volatile("s_waitcnt lgkmcnt(0)" ::: "memory")
#define WAIT_VM(n) asm volatile("s_waitcnt vmcnt(" #n ")" ::: "memory")

__device__ __forceinline__ unsigned short f2bf(float f) {
  unsigned int u = __builtin_bit_cast(unsigned int, f);
  u += 0x7fffu + ((u >> 16) & 1u);          // round-to-nearest-even
  return (unsigned short)(u >> 16);
}
__device__ __forceinline__ float bf2f(unsigned short b) {
  return __builtin_bit_cast(float, ((unsigned int)b) << 16);
}
__device__ __forceinline__ u16x8 pack8(f32x4 a, f32x4 b) {
  u16x8 o;
  o[0] = f2bf(a[0]); o[1] = f2bf(a[1]); o[2] = f2bf(a[2]); o[3] = f2bf(a[3]);
  o[4] = f2bf(b[0]); o[5] = f2bf(b[1]); o[6] = f2bf(b[2]); o[7] = f2bf(b[3]);
  return o;
}
// 8x f32 -> 8x bf16 via packed cvt (RNE)
__device__ __forceinline__ u16x8 cvt8(f32x4 a, f32x4 b) {
  union { unsigned int u[4]; u16x8 v; } r;
  asm("v_cvt_pk_bf16_f32 %0, %1, %2" : "=v"(r.u[0]) : "v"(a[0]), "v"(a[1]));
  asm("v_cvt_pk_bf16_f32 %0, %1, %2" : "=v"(r.u[1]) : "v"(a[2]), "v"(a[3]));
  asm("v_cvt_pk_bf16_f32 %0, %1, %2" : "=v"(r.u[2]) : "v"(b[0]), "v"(b[1]));
  asm("v_cvt_pk_bf16_f32 %0, %1, %2" : "=v"(r.u[3]) : "v"(b[2]), "v"(b[3]));
  return r.v;
}

__device__ __forceinline__ void gload_lds16(const unsigned short* g, unsigned short* l) {
  __builtin_amdgcn_global_load_lds(
      (const __attribute__((address_space(1))) unsigned int*)g,
      (__attribute__((address_space(3))) unsigned int*)l, 16, 0, 0);
}

// --------------------------------------------------- W -> bf16 (linear layout)
__global__ __launch_bounds__(256) void cvt_w(const float* __restrict__ Wq,
                                             const float* __restrict__ Wk,
                                             const float* __restrict__ Wv,
                                             unsigned short* __restrict__ Wb) {
  int i = blockIdx.x * 256 + threadIdx.x;     // 0 .. 393216 (3 * 131072 chunks of 8)
  int proj = i >> 17;
  int local = i & 131071;
  const float* src = (proj == 0 ? Wq : proj == 1 ? Wk : Wv) + (size_t)local * 8;
  f32x4 a = reinterpret_cast<const f32x4*>(src)[0];
  f32x4 b = reinterpret_cast<const f32x4*>(src)[1];
  *reinterpret_cast<u16x8*>(Wb + (size_t)proj * 1048576 + (size_t)local * 8) = pack8(a, b);
}

// ------------------------------------------------------------ QKV projection
// C[8192x1024] = X @ W^T + bias per proj.  BM=BN=128, BK=32, 256 threads,
// 4 waves (2x2), per-wave 64x64 (4x4 frags of 16x16x32 bf16 MFMA), 32 K-iters.

__device__ __forceinline__ void issueA(const float* __restrict__ X, int rowBase,
                                       int kt2, int t, f32x4 r[4]) {
  const int ra = t >> 2;                      // row 0..63 (and +64)
  const int sc = t & 3;                       // 8-elem k-slot
  const float* p0 = X + (size_t)(rowBase + ra) * 1024 + kt2 * 32 + sc * 8;
  const float* p1 = p0 + (size_t)64 * 1024;
  r[0] = *reinterpret_cast<const f32x4*>(p0);
  r[1] = *reinterpret_cast<const f32x4*>(p0 + 4);
  r[2] = *reinterpret_cast<const f32x4*>(p1);
  r[3] = *reinterpret_cast<const f32x4*>(p1 + 4);
}

__device__ __forceinline__ void writeA(unsigned short* As, int t, const f32x4 r[4]) {
  const int ra = t >> 2;
  const int sc = t & 3;
  const int r0 = ra, r1 = ra + 64;
  *reinterpret_cast<u16x8*>(As + r0 * 32 + ((sc ^ ((r0 >> 1) & 3)) * 8)) = cvt8(r[0], r[1]);
  *reinterpret_cast<u16x8*>(As + r1 * 32 + ((sc ^ ((r1 >> 1) & 3)) * 8)) = cvt8(r[2], r[3]);
}

__global__ __launch_bounds__(256, 4) void gemm5(
    const float* __restrict__ Xq, const float* __restrict__ Xk, const float* __restrict__ Xv,
    const unsigned short* __restrict__ Wb,
    const float* __restrict__ bq, const float* __restrict__ bk, const float* __restrict__ bv,
    unsigned short* __restrict__ QKV) {
  // XCD-family decode: XCD c (dispatch round-robin d%8) owns x in [8c,8c+8);
  // consecutive-in-time blocks on one XCD share x (X panel L2-resident, read
  // ~once from HBM) and sweep y (W panels cycle; L2+L3 absorb).
  const int d = blockIdx.x;
  const int xcd = d & 7;
  const int k5 = d >> 3;
  const int y = k5 & 7;
  const int rest = k5 >> 3;       // 0..23
  const int proj = rest >> 3;     // 0..2
  const int xg = rest & 7;
  const int x = xcd * 8 + xg;     // 0..63

  const float* X = (proj == 0) ? Xq : (proj == 1) ? Xk : Xv;
  const float* bias = (proj == 0) ? bq : (proj == 1) ? bk : bv;
  const unsigned short* W = Wb + (size_t)proj * 1048576;
  unsigned short* O = QKV + (size_t)proj * 8388608;

  const int rowBase = x * 128;
  const int colBase = y * 128;

  __shared__ alignas(16) unsigned short As[2][4096];   // [128 rows][32 k], chunk-XOR'd
  __shared__ alignas(16) unsigned short Bs[3][4096];   // 3-deep ring

  const int t = threadIdx.x;
  const int l = t & 63;
  const int w = t >> 6;
  const int wr = w >> 1, wc = w & 1;

  f32x4 acc[4][4];
#pragma unroll
  for (int m = 0; m < 4; ++m)
#pragma unroll
    for (int n = 0; n < 4; ++n) acc[m][n] = f32x4{0.f, 0.f, 0.f, 0.f};

  // fragment read offsets (ushort units), swizzle-matched: logical chunk g of
  // row r lives at physical chunk g ^ ((r>>1)&3)
  int aoff[4], boff[4];
#pragma unroll
  for (int m = 0; m < 4; ++m) {
    const int row = wr * 64 + m * 16 + (l & 15);
    aoff[m] = row * 32 + (((l >> 4) ^ ((row >> 1) & 3)) * 8);
  }
#pragma unroll
  for (int n = 0; n < 4; ++n) {
    const int row = wc * 64 + n * 16 + (l & 15);
    boff[n] = row * 32 + (((l >> 4) ^ ((row >> 1) & 3)) * 8);
  }

  // B staging: thread t, call j: linear dest byte o = (j*4+w)*1024 + l*16;
  // row = o>>6, phys chunk = l&3; source chunk = (l&3) ^ ((row>>1)&3)
  const int srow0 = w * 16 + (l >> 2);
  const int sc = l & 3;
#define STAGE_B(dst, kt)                                                          \
  {                                                                               \
    _Pragma("unroll") for (int j = 0; j < 2; ++j) {                               \
      const int row = j * 64 + srow0;                                             \
      const int cp = sc ^ ((row >> 1) & 3);                                       \
      gload_lds16(W + (size_t)(colBase + row) * 1024 + (kt) * 32 + cp * 8,        \
                  (dst) + (j * 4 + w) * 512 + l * 8);                             \
    }                                                                             \
  }

#define COMPUTE(abuf, bptr)                                                       \
  {                                                                               \
    bf16x8 af[4], bfr[4];                                                         \
    _Pragma("unroll") for (int m = 0; m < 4; ++m)                                 \
        af[m] = *reinterpret_cast<const bf16x8*>(&As[abuf][0] + aoff[m]);         \
    _Pragma("unroll") for (int n = 0; n < 4; ++n)                                 \
        bfr[n] = *reinterpret_cast<const bf16x8*>((bptr) + boff[n]);              \
    __builtin_amdgcn_s_setprio(1);                                                \
    _Pragma("unroll") for (int m = 0; m < 4; ++m)                                 \
        _Pragma("unroll") for (int n = 0; n < 4; ++n)                             \
            acc[m][n] =                                                           \
                __builtin_amdgcn_mfma_f32_16x16x32_bf16(af[m], bfr[n], acc[m][n], \
                                                        0, 0, 0);                 \
    __builtin_amdgcn_s_setprio(0);                                                \
  }

#define FENCE_SEQ                                                                 \
  __builtin_amdgcn_sched_barrier(0);                                              \
  __builtin_amdgcn_s_barrier();                                                   \
  __builtin_amdgcn_sched_barrier(0)

  f32x4 aRa[4], aRb[4];
  unsigned short* bufC = &Bs[0][0];
  unsigned short* bufN = &Bs[1][0];
  unsigned short* bufS = &Bs[2][0];

  // ---- prologue: As[0]+bufC <- tile 0; bufN <- tile 1 (in flight); aRa <- A(1)
  issueA(X, rowBase, 0, t, aRa);      // A(0) x4
  STAGE_B(bufC, 0);                   // glds(0) x2
  writeA(&As[0][0], t, aRa);          // compiler vmcnt(2): waits A(0), leaves glds(0)
  STAGE_B(bufN, 1);                   // glds(1) x2
  issueA(X, rowBase, 1, t, aRa);      // A(1) x4
  WAIT_LGKM0;
  WAIT_VM(6);                         // drain glds(0); leave glds(1)2 + A(1)4
  FENCE_SEQ;

  // ---- main loop (unroll 2 for reg ping-pong; B ring rotates by pointer)
  for (int kt = 0; kt < 32; kt += 2) {
    // even: compute tile kt (As[0], bufC); write As[1]<-aRa (kt+1);
    //        stage bufS <- glds(kt+2); aRb <- A(kt+2)
    {
      if (kt + 2 < 32) {
        STAGE_B(bufS, kt + 2);
        issueA(X, rowBase, kt + 2, t, aRb);
      }
      writeA(&As[1][0], t, aRa);      // compiler vmcnt(6): drains glds(kt+1)+A(kt+1)
      COMPUTE(0, bufC);
      WAIT_LGKM0;
      if (kt + 2 < 32) { WAIT_VM(6); } else { WAIT_VM(0); }
      FENCE_SEQ;
      unsigned short* tmp = bufC; bufC = bufN; bufN = bufS; bufS = tmp;
    }
    // odd: compute tile kt+1 (As[1], bufC); write As[0]<-aRb (kt+2);
    //        stage bufS <- glds(kt+3); aRa <- A(kt+3)
    {
      if (kt + 3 < 32) {
        STAGE_B(bufS, kt + 3);
        issueA(X, rowBase, kt + 3, t, aRa);
      }
      if (kt + 2 < 32) writeA(&As[0][0], t, aRb);
      COMPUTE(1, bufC);
      if (kt + 2 < 32) {
        WAIT_LGKM0;
        if (kt + 3 < 32) { WAIT_VM(6); } else { WAIT_VM(0); }
        FENCE_SEQ;
        unsigned short* tmp = bufC; bufC = bufN; bufN = bufS; bufS = tmp;
      }
    }
  }

  // ---- epilogue: C/D layout col=lane&15, row=(lane>>4)*4+reg
#pragma unroll
  for (int n = 0; n < 4; ++n) {
    const int col = colBase + wc * 64 + n * 16 + (l & 15);
    const float bn = bias[col];
#pragma unroll
    for (int m = 0; m < 4; ++m) {
      const int row0 = rowBase + wr * 64 + m * 16 + (l >> 4) * 4;
#pragma unroll
      for (int j = 0; j < 4; ++j)
        O[(size_t)(row0 + j) * 1024 + col] = f2bf(acc[m][n][j] + bn);
    }
  }
#undef STAGE_B
#undef COMPUTE
#undef FENCE_SEQ
}

// ------------------------------------------------------------------ attention
// thread = (n group, head h, d-quarter dq, row-half rh): 4 q-rows x 16 d-cols
// of the 8-key attention; QK partial dots reduced across 4 dq lanes.
__global__ __launch_bounds__(256) void attn_kernel(const unsigned short* __restrict__ QKV,
                                                   float* __restrict__ out) {
  const int t = threadIdx.x;
  const int lane = t & 63;
  const int dq = lane & 3;
  const int h = (lane >> 2) & 15;
  const int rh = (t >> 6) & 1;
  const int n = blockIdx.x * 2 + (t >> 7);

  const unsigned short* Q = QKV;
  const unsigned short* K = QKV + (size_t)8388608;
  const unsigned short* V = QKV + (size_t)16777216;
  const size_t gbase = (size_t)n * 8192;
  const int coff = h * 64 + dq * 16;

  float q[4][16];
#pragma unroll
  for (int r = 0; r < 4; ++r) {
    const unsigned short* qp = Q + gbase + (size_t)(rh * 4 + r) * 1024 + coff;
    u16x8 a = *reinterpret_cast<const u16x8*>(qp);
    u16x8 b = *reinterpret_cast<const u16x8*>(qp + 8);
#pragma unroll
    for (int c = 0; c < 8; ++c) { q[r][c] = bf2f(a[c]); q[r][8 + c] = bf2f(b[c]); }
  }

  float s[4][8];
#pragma unroll
  for (int r = 0; r < 4; ++r)
#pragma unroll
    for (int j = 0; j < 8; ++j) s[r][j] = 0.f;

#pragma unroll
  for (int j = 0; j < 8; ++j) {
    const unsigned short* kp = K + gbase + (size_t)j * 1024 + coff;
    u16x8 a = *reinterpret_cast<const u16x8*>(kp);
    u16x8 b = *reinterpret_cast<const u16x8*>(kp + 8);
    float kv[16];
#pragma unroll
    for (int c = 0; c < 8; ++c) { kv[c] = bf2f(a[c]); kv[8 + c] = bf2f(b[c]); }
#pragma unroll
    for (int r = 0; r < 4; ++r) {
      float acc = 0.f;
#pragma unroll
      for (int c = 0; c < 16; ++c) acc += q[r][c] * kv[c];
      s[r][j] += acc;
    }
  }

#pragma unroll
  for (int r = 0; r < 4; ++r)
#pragma unroll
    for (int j = 0; j < 8; ++j) {
      float v = s[r][j];
      v += __shfl_xor(v, 1, 64);
      v += __shfl_xor(v, 2, 64);
      s[r][j] = v;
    }

  float p[4][8];
#pragma unroll
  for (int r = 0; r < 4; ++r) {
    float mx = s[r][0];
#pragma unroll
    for (int j = 1; j < 8; ++j) mx = fmaxf(mx, s[r][j]);
    float sum = 0.f;
#pragma unroll
    for (int j = 0; j < 8; ++j) {
      float e = __expf(0.125f * (s[r][j] - mx));  // SCALE = 1/sqrt(64)
      p[r][j] = e;
      sum += e;
    }
    float inv = 1.f / sum;
#pragma unroll
    for (int j = 0; j < 8; ++j) p[r][j] *= inv;
  }

  float o[4][16];
#pragma unroll
  for (int r = 0; r < 4; ++r)
#pragma unroll
    for (int c = 0; c < 16; ++c) o[r][c] = 0.f;

#pragma unroll
  for (int j = 0; j < 8; ++j) {
    const unsigned short* vp = V + gbase + (size_t)j * 1024 + coff;
    u16x8 a = *reinterpret_cast<const u16x8*>(vp);
    u16x8 b = *reinterpret_cast<const u16x8*>(vp + 8);
    float vv[16];
#pragma unroll
    for (int c = 0; c < 8; ++c) { vv[c] = bf2f(a[c]); vv[8 + c] = bf2f(b[c]); }
#pragma unroll
    for (int r = 0; r < 4; ++r)
#pragma unroll
      for (int c = 0; c < 16; ++c) o[r][c] += p[r][j] * vv[c];
  }

#pragma unroll
  for (int r = 0; r < 4; ++r) {
    float* op = out + gbase + (size_t)(rh * 4 + r) * 1024 + coff;
    f32x4 v0 = {o[r][0], o[r][1], o[r][2], o[r][3]};
    f32x4 v1 = {o[r][4], o[r][5], o[r][6], o[r][7]};
    f32x4 v2 = {o[r][8], o[r][9], o[r][10], o[r][11]};
    f32x4 v3 = {o[r][12], o[r][13], o[r][14], o[r][15]};
    reinterpret_cast<f32x4*>(op)[0] = v0;
    reinterpret_cast<f32x4*>(op)[1] = v1;
    reinterpret_cast<f32x4*>(op)[2] = v2;
    reinterpret_cast<f32x4*>(op)[3] = v3;
  }
}

// ------------------------------------------------------------------- launch
extern "C" void kernel_launch(void* const* d_in, const int* in_sizes, int n_in,
                              void* d_out, int out_size, void* d_ws, size_t ws_size,
                              hipStream_t stream) {
  const float* Xq = (const float*)d_in[0];
  const float* Xk = (const float*)d_in[1];
  const float* Xv = (const float*)d_in[2];
  const float* Wq = (const float*)d_in[3];
  const float* bq = (const float*)d_in[4];
  const float* Wk = (const float*)d_in[5];
  const float* bk = (const float*)d_in[6];
  const float* Wv = (const float*)d_in[7];
  const float* bv = (const float*)d_in[8];

  unsigned short* ws = (unsigned short*)d_ws;
  unsigned short* Wb = ws;                              // 3 x 1M bf16 (6 MB), linear
  unsigned short* QKV = ws + (size_t)3 * 1024 * 1024;   // 3 x 8M bf16 (48 MB)

  cvt_w<<<1536, 256, 0, stream>>>(Wq, Wk, Wv, Wb);
  gemm5<<<1536, 256, 0, stream>>>(Xq, Xk, Xv, Wb, bq, bk, bv, QKV);
  attn_kernel<<<512, 256, 0, stream>>>(QKV, (float*)d_out);
}

// Round 6
// 100.440 us; speedup vs baseline: 1.5972x; 1.5972x over previous
//
#include <hip/hip_runtime.h>

// MultiHeadAttention_137438953529 on gfx950.
// B=8, S=1024, E=1024, H=16, D=64.  The reference's reshapes are flat
// reinterpretations => attention mixes only groups of 8 consecutive rows of
// the (8192 x 1024) projected matrices, per 64-wide head slice.
//
// R6: R5's 3-buffer B ring was correct but ran SPILL-BOUND: launch_bounds
// (256,4) capped unified VGPR+AGPR at 128/lane; acc=64 AGPR + prefetch regs
// overflowed -> ~200 MB scratch writes (WRITE_SIZE 52->247 MB), MfmaUtil 10%.
// Fix: launch_bounds(256,3) (~170-reg budget, spill-free like R4) and keep
// the 2-tile-deep B pipeline.
// Kept: XCD-family decode (FETCH ~82 MB), source-side chunk XOR (0 bank
// conflicts), cvt_pk A-path (2-iter-ahead reg prefetch), m97 epilogue.

typedef __attribute__((ext_vector_type(4))) float f32x4;
typedef __attribute__((ext_vector_type(8))) short bf16x8;   // MFMA A/B fragment
typedef __attribute__((ext_vector_type(8))) unsigned short u16x8;

#define WAIT_LGKM0 asm volatile("s_waitcnt lgkmcnt(0)" ::: "memory")
#define WAIT_VM(n) asm volatile("s_waitcnt vmcnt(" #n ")" ::: "memory")

__device__ __forceinline__ unsigned short f2bf(float f) {
  unsigned int u = __builtin_bit_cast(unsigned int, f);
  u += 0x7fffu + ((u >> 16) & 1u);          // round-to-nearest-even
  return (unsigned short)(u >> 16);
}
__device__ __forceinline__ float bf2f(unsigned short b) {
  return __builtin_bit_cast(float, ((unsigned int)b) << 16);
}
__device__ __forceinline__ u16x8 pack8(f32x4 a, f32x4 b) {
  u16x8 o;
  o[0] = f2bf(a[0]); o[1] = f2bf(a[1]); o[2] = f2bf(a[2]); o[3] = f2bf(a[3]);
  o[4] = f2bf(b[0]); o[5] = f2bf(b[1]); o[6] = f2bf(b[2]); o[7] = f2bf(b[3]);
  return o;
}
// 8x f32 -> 8x bf16 via packed cvt (RNE)
__device__ __forceinline__ u16x8 cvt8(f32x4 a, f32x4 b) {
  union { unsigned int u[4]; u16x8 v; } r;
  asm("v_cvt_pk_bf16_f32 %0, %1, %2" : "=v"(r.u[0]) : "v"(a[0]), "v"(a[1]));
  asm("v_cvt_pk_bf16_f32 %0, %1, %2" : "=v"(r.u[1]) : "v"(a[2]), "v"(a[3]));
  asm("v_cvt_pk_bf16_f32 %0, %1, %2" : "=v"(r.u[2]) : "v"(b[0]), "v"(b[1]));
  asm("v_cvt_pk_bf16_f32 %0, %1, %2" : "=v"(r.u[3]) : "v"(b[2]), "v"(b[3]));
  return r.v;
}

__device__ __forceinline__ void gload_lds16(const unsigned short* g, unsigned short* l) {
  __builtin_amdgcn_global_load_lds(
      (const __attribute__((address_space(1))) unsigned int*)g,
      (__attribute__((address_space(3))) unsigned int*)l, 16, 0, 0);
}

// --------------------------------------------------- W -> bf16 (linear layout)
__global__ __launch_bounds__(256) void cvt_w(const float* __restrict__ Wq,
                                             const float* __restrict__ Wk,
                                             const float* __restrict__ Wv,
                                             unsigned short* __restrict__ Wb) {
  int i = blockIdx.x * 256 + threadIdx.x;     // 0 .. 393216 (3 * 131072 chunks of 8)
  int proj = i >> 17;
  int local = i & 131071;
  const float* src = (proj == 0 ? Wq : proj == 1 ? Wk : Wv) + (size_t)local * 8;
  f32x4 a = reinterpret_cast<const f32x4*>(src)[0];
  f32x4 b = reinterpret_cast<const f32x4*>(src)[1];
  *reinterpret_cast<u16x8*>(Wb + (size_t)proj * 1048576 + (size_t)local * 8) = pack8(a, b);
}

// ------------------------------------------------------------ QKV projection
// C[8192x1024] = X @ W^T + bias per proj.  BM=BN=128, BK=32, 256 threads,
// 4 waves (2x2), per-wave 64x64 (4x4 frags of 16x16x32 bf16 MFMA), 32 K-iters.

__device__ __forceinline__ void issueA(const float* __restrict__ X, int rowBase,
                                       int kt2, int t, f32x4 r[4]) {
  const int ra = t >> 2;                      // row 0..63 (and +64)
  const int sc = t & 3;                       // 8-elem k-slot
  const float* p0 = X + (size_t)(rowBase + ra) * 1024 + kt2 * 32 + sc * 8;
  const float* p1 = p0 + (size_t)64 * 1024;
  r[0] = *reinterpret_cast<const f32x4*>(p0);
  r[1] = *reinterpret_cast<const f32x4*>(p0 + 4);
  r[2] = *reinterpret_cast<const f32x4*>(p1);
  r[3] = *reinterpret_cast<const f32x4*>(p1 + 4);
}

__device__ __forceinline__ void writeA(unsigned short* As, int t, const f32x4 r[4]) {
  const int ra = t >> 2;
  const int sc = t & 3;
  const int r0 = ra, r1 = ra + 64;
  *reinterpret_cast<u16x8*>(As + r0 * 32 + ((sc ^ ((r0 >> 1) & 3)) * 8)) = cvt8(r[0], r[1]);
  *reinterpret_cast<u16x8*>(As + r1 * 32 + ((sc ^ ((r1 >> 1) & 3)) * 8)) = cvt8(r[2], r[3]);
}

__global__ __launch_bounds__(256, 3) void gemm6(
    const float* __restrict__ Xq, const float* __restrict__ Xk, const float* __restrict__ Xv,
    const unsigned short* __restrict__ Wb,
    const float* __restrict__ bq, const float* __restrict__ bk, const float* __restrict__ bv,
    unsigned short* __restrict__ QKV) {
  // XCD-family decode: XCD c (dispatch round-robin d%8) owns x in [8c,8c+8);
  // consecutive-in-time blocks on one XCD share x (X panel L2-resident, read
  // ~once from HBM) and sweep y (W panels cycle; L2+L3 absorb).
  const int d = blockIdx.x;
  const int xcd = d & 7;
  const int k5 = d >> 3;
  const int y = k5 & 7;
  const int rest = k5 >> 3;       // 0..23
  const int proj = rest >> 3;     // 0..2
  const int xg = rest & 7;
  const int x = xcd * 8 + xg;     // 0..63

  const float* X = (proj == 0) ? Xq : (proj == 1) ? Xk : Xv;
  const float* bias = (proj == 0) ? bq : (proj == 1) ? bk : bv;
  const unsigned short* W = Wb + (size_t)proj * 1048576;
  unsigned short* O = QKV + (size_t)proj * 8388608;

  const int rowBase = x * 128;
  const int colBase = y * 128;

  __shared__ alignas(16) unsigned short As[2][4096];   // [128 rows][32 k], chunk-XOR'd
  __shared__ alignas(16) unsigned short Bs[3][4096];   // 3-deep ring

  const int t = threadIdx.x;
  const int l = t & 63;
  const int w = t >> 6;
  const int wr = w >> 1, wc = w & 1;

  f32x4 acc[4][4];
#pragma unroll
  for (int m = 0; m < 4; ++m)
#pragma unroll
    for (int n = 0; n < 4; ++n) acc[m][n] = f32x4{0.f, 0.f, 0.f, 0.f};

  // fragment read offsets (ushort units), swizzle-matched: logical chunk g of
  // row r lives at physical chunk g ^ ((r>>1)&3)
  int aoff[4], boff[4];
#pragma unroll
  for (int m = 0; m < 4; ++m) {
    const int row = wr * 64 + m * 16 + (l & 15);
    aoff[m] = row * 32 + (((l >> 4) ^ ((row >> 1) & 3)) * 8);
  }
#pragma unroll
  for (int n = 0; n < 4; ++n) {
    const int row = wc * 64 + n * 16 + (l & 15);
    boff[n] = row * 32 + (((l >> 4) ^ ((row >> 1) & 3)) * 8);
  }

  // B staging: thread t, call j: linear dest byte o = (j*4+w)*1024 + l*16;
  // row = o>>6, phys chunk = l&3; source chunk = (l&3) ^ ((row>>1)&3)
  const int srow0 = w * 16 + (l >> 2);
  const int sc = l & 3;
#define STAGE_B(dst, kt)                                                          \
  {                                                                               \
    _Pragma("unroll") for (int j = 0; j < 2; ++j) {                               \
      const int row = j * 64 + srow0;                                             \
      const int cp = sc ^ ((row >> 1) & 3);                                       \
      gload_lds16(W + (size_t)(colBase + row) * 1024 + (kt) * 32 + cp * 8,        \
                  (dst) + (j * 4 + w) * 512 + l * 8);                             \
    }                                                                             \
  }

#define COMPUTE(abuf, bptr)                                                       \
  {                                                                               \
    bf16x8 af[4], bfr[4];                                                         \
    _Pragma("unroll") for (int m = 0; m < 4; ++m)                                 \
        af[m] = *reinterpret_cast<const bf16x8*>(&As[abuf][0] + aoff[m]);         \
    _Pragma("unroll") for (int n = 0; n < 4; ++n)                                 \
        bfr[n] = *reinterpret_cast<const bf16x8*>((bptr) + boff[n]);              \
    __builtin_amdgcn_s_setprio(1);                                                \
    _Pragma("unroll") for (int m = 0; m < 4; ++m)                                 \
        _Pragma("unroll") for (int n = 0; n < 4; ++n)                             \
            acc[m][n] =                                                           \
                __builtin_amdgcn_mfma_f32_16x16x32_bf16(af[m], bfr[n], acc[m][n], \
                                                        0, 0, 0);                 \
    __builtin_amdgcn_s_setprio(0);                                                \
  }

#define FENCE_SEQ                                                                 \
  __builtin_amdgcn_sched_barrier(0);                                              \
  __builtin_amdgcn_s_barrier();                                                   \
  __builtin_amdgcn_sched_barrier(0)

  f32x4 aRa[4], aRb[4];
  unsigned short* bufC = &Bs[0][0];
  unsigned short* bufN = &Bs[1][0];
  unsigned short* bufS = &Bs[2][0];

  // ---- prologue: As[0]+bufC <- tile 0; bufN <- tile 1 (in flight); aRa <- A(1)
  issueA(X, rowBase, 0, t, aRa);      // A(0) x4
  STAGE_B(bufC, 0);                   // glds(0) x2
  writeA(&As[0][0], t, aRa);          // compiler vmcnt(2): waits A(0), leaves glds(0)
  STAGE_B(bufN, 1);                   // glds(1) x2
  issueA(X, rowBase, 1, t, aRa);      // A(1) x4
  WAIT_LGKM0;
  WAIT_VM(6);                         // drain glds(0); leave glds(1)2 + A(1)4
  FENCE_SEQ;

  // ---- main loop (unroll 2 for reg ping-pong; B ring rotates by pointer)
  for (int kt = 0; kt < 32; kt += 2) {
    // even: compute tile kt (As[0], bufC); write As[1]<-aRa (kt+1);
    //        stage bufS <- glds(kt+2); aRb <- A(kt+2)
    {
      if (kt + 2 < 32) {
        STAGE_B(bufS, kt + 2);
        issueA(X, rowBase, kt + 2, t, aRb);
      }
      writeA(&As[1][0], t, aRa);      // compiler vmcnt(6): drains glds(kt+1)+A(kt+1)
      COMPUTE(0, bufC);
      WAIT_LGKM0;
      if (kt + 2 < 32) { WAIT_VM(6); } else { WAIT_VM(0); }
      FENCE_SEQ;
      unsigned short* tmp = bufC; bufC = bufN; bufN = bufS; bufS = tmp;
    }
    // odd: compute tile kt+1 (As[1], bufC); write As[0]<-aRb (kt+2);
    //        stage bufS <- glds(kt+3); aRa <- A(kt+3)
    {
      if (kt + 3 < 32) {
        STAGE_B(bufS, kt + 3);
        issueA(X, rowBase, kt + 3, t, aRa);
      }
      if (kt + 2 < 32) writeA(&As[0][0], t, aRb);
      COMPUTE(1, bufC);
      if (kt + 2 < 32) {
        WAIT_LGKM0;
        if (kt + 3 < 32) { WAIT_VM(6); } else { WAIT_VM(0); }
        FENCE_SEQ;
        unsigned short* tmp = bufC; bufC = bufN; bufN = bufS; bufS = tmp;
      }
    }
  }

  // ---- epilogue: C/D layout col=lane&15, row=(lane>>4)*4+reg
#pragma unroll
  for (int n = 0; n < 4; ++n) {
    const int col = colBase + wc * 64 + n * 16 + (l & 15);
    const float bn = bias[col];
#pragma unroll
    for (int m = 0; m < 4; ++m) {
      const int row0 = rowBase + wr * 64 + m * 16 + (l >> 4) * 4;
#pragma unroll
      for (int j = 0; j < 4; ++j)
        O[(size_t)(row0 + j) * 1024 + col] = f2bf(acc[m][n][j] + bn);
    }
  }
#undef STAGE_B
#undef COMPUTE
#undef FENCE_SEQ
}

// ------------------------------------------------------------------ attention
// thread = (n group, head h, d-quarter dq, row-half rh): 4 q-rows x 16 d-cols
// of the 8-key attention; QK partial dots reduced across 4 dq lanes.
__global__ __launch_bounds__(256) void attn_kernel(const unsigned short* __restrict__ QKV,
                                                   float* __restrict__ out) {
  const int t = threadIdx.x;
  const int lane = t & 63;
  const int dq = lane & 3;
  const int h = (lane >> 2) & 15;
  const int rh = (t >> 6) & 1;
  const int n = blockIdx.x * 2 + (t >> 7);

  const unsigned short* Q = QKV;
  const unsigned short* K = QKV + (size_t)8388608;
  const unsigned short* V = QKV + (size_t)16777216;
  const size_t gbase = (size_t)n * 8192;
  const int coff = h * 64 + dq * 16;

  float q[4][16];
#pragma unroll
  for (int r = 0; r < 4; ++r) {
    const unsigned short* qp = Q + gbase + (size_t)(rh * 4 + r) * 1024 + coff;
    u16x8 a = *reinterpret_cast<const u16x8*>(qp);
    u16x8 b = *reinterpret_cast<const u16x8*>(qp + 8);
#pragma unroll
    for (int c = 0; c < 8; ++c) { q[r][c] = bf2f(a[c]); q[r][8 + c] = bf2f(b[c]); }
  }

  float s[4][8];
#pragma unroll
  for (int r = 0; r < 4; ++r)
#pragma unroll
    for (int j = 0; j < 8; ++j) s[r][j] = 0.f;

#pragma unroll
  for (int j = 0; j < 8; ++j) {
    const unsigned short* kp = K + gbase + (size_t)j * 1024 + coff;
    u16x8 a = *reinterpret_cast<const u16x8*>(kp);
    u16x8 b = *reinterpret_cast<const u16x8*>(kp + 8);
    float kv[16];
#pragma unroll
    for (int c = 0; c < 8; ++c) { kv[c] = bf2f(a[c]); kv[8 + c] = bf2f(b[c]); }
#pragma unroll
    for (int r = 0; r < 4; ++r) {
      float acc = 0.f;
#pragma unroll
      for (int c = 0; c < 16; ++c) acc += q[r][c] * kv[c];
      s[r][j] += acc;
    }
  }

#pragma unroll
  for (int r = 0; r < 4; ++r)
#pragma unroll
    for (int j = 0; j < 8; ++j) {
      float v = s[r][j];
      v += __shfl_xor(v, 1, 64);
      v += __shfl_xor(v, 2, 64);
      s[r][j] = v;
    }

  float p[4][8];
#pragma unroll
  for (int r = 0; r < 4; ++r) {
    float mx = s[r][0];
#pragma unroll
    for (int j = 1; j < 8; ++j) mx = fmaxf(mx, s[r][j]);
    float sum = 0.f;
#pragma unroll
    for (int j = 0; j < 8; ++j) {
      float e = __expf(0.125f * (s[r][j] - mx));  // SCALE = 1/sqrt(64)
      p[r][j] = e;
      sum += e;
    }
    float inv = 1.f / sum;
#pragma unroll
    for (int j = 0; j < 8; ++j) p[r][j] *= inv;
  }

  float o[4][16];
#pragma unroll
  for (int r = 0; r < 4; ++r)
#pragma unroll
    for (int c = 0; c < 16; ++c) o[r][c] = 0.f;

#pragma unroll
  for (int j = 0; j < 8; ++j) {
    const unsigned short* vp = V + gbase + (size_t)j * 1024 + coff;
    u16x8 a = *reinterpret_cast<const u16x8*>(vp);
    u16x8 b = *reinterpret_cast<const u16x8*>(vp + 8);
    float vv[16];
#pragma unroll
    for (int c = 0; c < 8; ++c) { vv[c] = bf2f(a[c]); vv[8 + c] = bf2f(b[c]); }
#pragma unroll
    for (int r = 0; r < 4; ++r)
#pragma unroll
      for (int c = 0; c < 16; ++c) o[r][c] += p[r][j] * vv[c];
  }

#pragma unroll
  for (int r = 0; r < 4; ++r) {
    float* op = out + gbase + (size_t)(rh * 4 + r) * 1024 + coff;
    f32x4 v0 = {o[r][0], o[r][1], o[r][2], o[r][3]};
    f32x4 v1 = {o[r][4], o[r][5], o[r][6], o[r][7]};
    f32x4 v2 = {o[r][8], o[r][9], o[r][10], o[r][11]};
    f32x4 v3 = {o[r][12], o[r][13], o[r][14], o[r][15]};
    reinterpret_cast<f32x4*>(op)[0] = v0;
    reinterpret_cast<f32x4*>(op)[1] = v1;
    reinterpret_cast<f32x4*>(op)[2] = v2;
    reinterpret_cast<f32x4*>(op)[3] = v3;
  }
}

// ------------------------------------------------------------------- launch
extern "C" void kernel_launch(void* const* d_in, const int* in_sizes, int n_in,
                              void* d_out, int out_size, void* d_ws, size_t ws_size,
                              hipStream_t stream) {
  const float* Xq = (const float*)d_in[0];
  const float* Xk = (const float*)d_in[1];
  const float* Xv = (const float*)d_in[2];
  const float* Wq = (const float*)d_in[3];
  const float* bq = (const float*)d_in[4];
  const float* Wk = (const float*)d_in[5];
  const float* bk = (const float*)d_in[6];
  const float* Wv = (const float*)d_in[7];
  const float* bv = (const float*)d_in[8];

  unsigned short* ws = (unsigned short*)d_ws;
  unsigned short* Wb = ws;                              // 3 x 1M bf16 (6 MB), linear
  unsigned short* QKV = ws + (size_t)3 * 1024 * 1024;   // 3 x 8M bf16 (48 MB)

  cvt_w<<<1536, 256, 0, stream>>>(Wq, Wk, Wv, Wb);
  gemm6<<<1536, 256, 0, stream>>>(Xq, Xk, Xv, Wb, bq, bk, bv, QKV);
  attn_kernel<<<512, 256, 0, stream>>>(QKV, (float*)d_out);
}